// Round 4
// baseline (274.724 us; speedup 1.0000x reference)
//
#include <hip/hip_runtime.h>

namespace {
constexpr int S_LEN = 512;
constexpr int BATCH = 1024;
constexpr int TAG = 64;
constexpr int START_IDX = 0;
constexpr int END_IDX = 1;
constexpr float NEG_INF = -10000.0f;
constexpr int CHUNK = 64;              // steps per LDS chunk (16 KB)
constexpr float LN2F = 0.69314718055994530942f;

typedef float v2f __attribute__((ext_vector_type(2)));
typedef float v4f __attribute__((ext_vector_type(4)));

typedef const __attribute__((address_space(1))) void* gas_ptr;
typedef __attribute__((address_space(3))) void* las_ptr;

__device__ inline void gld_lds16(const float* g, float* l) {
  // LDS dest = wave-uniform base + lane*16 (hardware); global src is per-lane.
  __builtin_amdgcn_global_load_lds((gas_ptr)(const void*)g, (las_ptr)(void*)l, 16, 0, 0);
}
}

// One wave (64 lanes) per batch; lane = destination tag j.
// Linear-domain recurrence: p_j = exp(alpha_j - etot*ln2), exact power-of-2 renorm
// from exponent bits of lane 2's p.  t_j = sum_i E[j,i] * p_i, split across pipes:
//   i = 0..31  -> LDS broadcast (ds_write p, 8x ds_read_b128, 16x v_pk_fma_f32)
//   i = 32..63 -> v_readlane -> SGPR -> v_fmac (hoisted 16-apart to dodge the
//                 VALU-writes-SGPR hazard)
// The DS round-trip and the readlane/fmac stream run on different pipes and overlap.
// Feats staged 64 steps ahead into double-buffered LDS; exp(feat) batched off-chain.
__global__ __launch_bounds__(64, 1) void crf_fwd_kernel(
    const float* __restrict__ feats,   // [S, B, T]
    const float* __restrict__ mask,    // [S, B]
    const float* __restrict__ trans,   // [T, T]
    float* __restrict__ out) {         // [B]
  const int b = blockIdx.x;
  const int lane = threadIdx.x;  // tag j

  __shared__ __align__(16) float fchunk[2][CHUNK * TAG];  // 2 x 16 KB
  __shared__ __align__(16) float p_lds[TAG];

  // ---- effective length L = sum_s mask[s,b] (mask monotone non-increasing) ----
  int L;
  {
    float sum = 0.0f;
#pragma unroll
    for (int k = 0; k < S_LEN / 64; ++k) sum += mask[(size_t)(lane + 64 * k) * BATCH + b];
#pragma unroll
    for (int off = 32; off >= 1; off >>= 1) sum += __shfl_xor(sum, off, 64);
    L = (int)(sum + 0.5f);
  }

  // ---- one-time: E row j (exp of transition row); lower half as v2f for pk_fma,
  //      upper half as scalars for the readlane/fmac path ----
  v2f El[16];    // E[j][0..31]
  float Eu[32];  // E[j][32..63]
  {
    const float* row = trans + lane * TAG;
#pragma unroll
    for (int k = 0; k < 8; ++k) {
      v4f tv;
      __builtin_memcpy(&tv, row + 4 * k, sizeof(v4f));
      El[2 * k]     = v2f{__expf(tv.x), __expf(tv.y)};  // exp(-10000) -> 0, no NaN
      El[2 * k + 1] = v2f{__expf(tv.z), __expf(tv.w)};
    }
#pragma unroll
    for (int k = 0; k < 8; ++k) {
      v4f tv;
      __builtin_memcpy(&tv, row + 32 + 4 * k, sizeof(v4f));
      Eu[4 * k + 0] = __expf(tv.x);
      Eu[4 * k + 1] = __expf(tv.y);
      Eu[4 * k + 2] = __expf(tv.z);
      Eu[4 * k + 3] = __expf(tv.w);
    }
  }

  // per-lane invariant staging address: one gld_lds16 moves 4 rows (4 x 256 B)
  const float* gstage0 =
      feats + ((size_t)(lane >> 4) * BATCH + b) * TAG + ((lane & 15) << 2);

  auto stage_chunk = [&](int base_s, int nb) {
    const float* g0 = gstage0 + (size_t)base_s * (BATCH * TAG);
#pragma unroll
    for (int q = 0; q < 16; ++q) {
      gld_lds16(g0 + (size_t)(4 * q) * (BATCH * TAG), &fchunk[nb][q * 256]);
    }
  };

  float p = (lane == START_IDX) ? 1.0f : 0.0f;
  int etot = 0;  // running power-of-2 count: M = etot * ln2 (exact scaling)

  // ---- prologue: stage chunk 0 and wait for it ----
  stage_chunk(0, 0);
  asm volatile("s_waitcnt vmcnt(0)" ::: "memory");
  __builtin_amdgcn_sched_barrier(0);
  __builtin_amdgcn_wave_barrier();

  // one step; chain = DS round-trip (lower half) overlapped with readlane stream
  auto step = [&](float ex) {
    const unsigned pu = __float_as_uint(p);

    // anchor renorm (uniform/SALU; overlaps everything below)
    const unsigned pb = __builtin_amdgcn_readlane(pu, 2);
    const unsigned eb = (pb == 0u) ? 127u : (pb >> 23);
    etot += (int)eb - 127;
    const float scale = __uint_as_float((254u - eb) << 23);  // 2^(127-eb), exact
    const float cg = ex * scale;

    // ---- LDS half: write p, issue 8 broadcast b128 reads of p[0..31] ----
    p_lds[lane] = p;
    __builtin_amdgcn_wave_barrier();  // pin: reads below stay after the write
    v4f q0, q1, q2, q3, q4, q5, q6, q7;
    __builtin_memcpy(&q0, p_lds + 0,  sizeof(v4f));
    __builtin_memcpy(&q1, p_lds + 4,  sizeof(v4f));
    __builtin_memcpy(&q2, p_lds + 8,  sizeof(v4f));
    __builtin_memcpy(&q3, p_lds + 12, sizeof(v4f));
    __builtin_memcpy(&q4, p_lds + 16, sizeof(v4f));
    __builtin_memcpy(&q5, p_lds + 20, sizeof(v4f));
    __builtin_memcpy(&q6, p_lds + 24, sizeof(v4f));
    __builtin_memcpy(&q7, p_lds + 28, sizeof(v4f));

    // ---- readlane half (i = 32..63): hoist 16 readlanes, then 16 fmacs ----
    float t0 = 0.f, t1 = 0.f, t2 = 0.f, t3 = 0.f;
    {
      float r[16];
#pragma unroll
      for (int k = 0; k < 16; ++k)
        r[k] = __uint_as_float(__builtin_amdgcn_readlane(pu, 32 + k));
#pragma unroll
      for (int k = 0; k < 16; k += 4) {
        t0 = __builtin_fmaf(r[k + 0], Eu[k + 0], t0);
        t1 = __builtin_fmaf(r[k + 1], Eu[k + 1], t1);
        t2 = __builtin_fmaf(r[k + 2], Eu[k + 2], t2);
        t3 = __builtin_fmaf(r[k + 3], Eu[k + 3], t3);
      }
    }
    {
      float r[16];
#pragma unroll
      for (int k = 0; k < 16; ++k)
        r[k] = __uint_as_float(__builtin_amdgcn_readlane(pu, 48 + k));
#pragma unroll
      for (int k = 0; k < 16; k += 4) {
        t0 = __builtin_fmaf(r[k + 0], Eu[16 + k + 0], t0);
        t1 = __builtin_fmaf(r[k + 1], Eu[16 + k + 1], t1);
        t2 = __builtin_fmaf(r[k + 2], Eu[16 + k + 2], t2);
        t3 = __builtin_fmaf(r[k + 3], Eu[16 + k + 3], t3);
      }
    }

    // ---- LDS half consumes (compiler waits lgkmcnt right before first use) ----
    v2f c0 = {0.f, 0.f}, c1 = {0.f, 0.f}, c2 = {0.f, 0.f}, c3 = {0.f, 0.f};
    c0 += v2f{q0.x, q0.y} * El[0];  c1 += v2f{q0.z, q0.w} * El[1];
    c2 += v2f{q1.x, q1.y} * El[2];  c3 += v2f{q1.z, q1.w} * El[3];
    c0 += v2f{q2.x, q2.y} * El[4];  c1 += v2f{q2.z, q2.w} * El[5];
    c2 += v2f{q3.x, q3.y} * El[6];  c3 += v2f{q3.z, q3.w} * El[7];
    c0 += v2f{q4.x, q4.y} * El[8];  c1 += v2f{q4.z, q4.w} * El[9];
    c2 += v2f{q5.x, q5.y} * El[10]; c3 += v2f{q5.z, q5.w} * El[11];
    c0 += v2f{q6.x, q6.y} * El[12]; c1 += v2f{q6.z, q6.w} * El[13];
    c2 += v2f{q7.x, q7.y} * El[14]; c3 += v2f{q7.z, q7.w} * El[15];

    const v2f cs = (c0 + c1) + (c2 + c3);
    const float tl = cs.x + cs.y;
    const float tu = (t0 + t1) + (t2 + t3);
    p = (tl + tu) * cg;

    __builtin_amdgcn_wave_barrier();  // WAR: next step's ds_write after these reads
  };

  for (int c = 0;; ++c) {
    const int base = c * CHUNK;
    int n = L - base;
    if (n <= 0) break;
    if (n > CHUNK) n = CHUNK;

    const int nbase = base + CHUNK;
    if (nbase < S_LEN) stage_chunk(nbase, (c + 1) & 1);  // async, 64 steps ahead

    const float* fb = &fchunk[c & 1][0];

    // 8-step groups: feat reads + exp batched off-chain
    auto group8 = [&](int s0) {
      float ex[8];
#pragma unroll
      for (int i = 0; i < 8; ++i) ex[i] = fb[(s0 + i) * TAG + lane];
#pragma unroll
      for (int i = 0; i < 8; ++i) ex[i] = __expf(ex[i]);
#pragma unroll
      for (int i = 0; i < 8; ++i) step(ex[i]);
    };

    if (n == CHUNK) {
      for (int g = 0; g < CHUNK / 8; ++g) group8(8 * g);
    } else {
      const int full = n >> 3;
      for (int g = 0; g < full; ++g) group8(8 * g);
      for (int i = full * 8; i < n; ++i) {  // tail (rare): on-chain exp is fine here
        step(__expf(fb[i * TAG + lane]));
      }
      break;  // L reached inside this chunk
    }

    if (nbase >= L) break;  // done; skip the drain

    // next chunk's loads were issued 64 steps ago: drain is ~free
    asm volatile("s_waitcnt vmcnt(0)" ::: "memory");
    __builtin_amdgcn_sched_barrier(0);
    __builtin_amdgcn_wave_barrier();
  }

  // drain any in-flight staging before LDS is deallocated at wave exit
  asm volatile("s_waitcnt vmcnt(0)" ::: "memory");

  // ---- epilogue: out[b] = logsumexp_j(etot*ln2 + log p_j + trans[END, j]) ----
  {
    const float a = (float)etot * LN2F + __logf(p) + trans[END_IDX * TAG + lane];
    float mx = a;  // p==0 -> a=-inf; lane 2 always finite so mx finite
#pragma unroll
    for (int off = 32; off >= 1; off >>= 1) mx = fmaxf(mx, __shfl_xor(mx, off, 64));
    float e = __expf(a - mx);
#pragma unroll
    for (int off = 32; off >= 1; off >>= 1) e += __shfl_xor(e, off, 64);
    if (lane == 0) out[b] = mx + __logf(e);
  }
}

extern "C" void kernel_launch(void* const* d_in, const int* in_sizes, int n_in,
                              void* d_out, int out_size, void* d_ws, size_t ws_size,
                              hipStream_t stream) {
  const float* feats = (const float*)d_in[0];
  const float* mask = (const float*)d_in[1];
  const float* trans = (const float*)d_in[2];
  float* out = (float*)d_out;
  crf_fwd_kernel<<<dim3(BATCH), dim3(64), 0, stream>>>(feats, mask, trans, out);
}